// Round 5
// baseline (708.624 us; speedup 1.0000x reference)
//
#include <hip/hip_runtime.h>

// Problem constants: B=4, C=64, H=256, W=448, fp32.
#define BB 4
#define CC 64
#define HH 256
#define WW 448
constexpr int HW  = HH * WW;    // 114688
constexpr int CHW = CC * HW;    // 7340032

// Gather-tile geometry
#define TX 32                   // tile width  (W=448 -> 14 tiles)
#define TY 16                   // tile height (H=256 -> 16 tiles)
#define TH 7                    // source window halo; "local" iff |d| <= 6
#define LOCAL_MAX 6.0f
#define WINX (TX + 2*TH)        // 46
#define WINY (TY + 2*TH)        // 30
#define NSRC (WINX * WINY)      // 1380
#define TPB 256
#define MAXK 6                  // ceil(NSRC / TPB)
#define KCH 3                   // window k-iters per compaction round
#define NROUND 2                // MAXK / KCH
#define CAP (KCH * TPB)         // 768: list capacity == max appended per round
#define NCH 8                   // channels per block (chunk-group)
#define NGRP (CC / NCH)         // 8
#define TXTY (TX * TY)          // 512

// ws layout (floats): [0, B*HW) = weight accumulator (outliers only);
//                     [B*HW]    = outlier flag (as u32)

// ---------------------------------------------------------------------------
// K1: detect any source pixel with |flow| > LOCAL_MAX (rare path trigger).
// ---------------------------------------------------------------------------
__global__ __launch_bounds__(TPB) void flag_kernel(
    const float* __restrict__ flow, unsigned* __restrict__ flag)
{
    int p = blockIdx.x * TPB + threadIdx.x;
    if (p >= BB * HW) return;
    int b = p / HW, rem = p - b * HW;
    float dx = flow[(b * 2 + 0) * HW + rem];
    float dy = flow[(b * 2 + 1) * HW + rem];
    if (!((fabsf(dx) <= LOCAL_MAX) && (fabsf(dy) <= LOCAL_MAX)))
        atomicOr(flag, 1u);
}

// ---------------------------------------------------------------------------
// K2: zero d_out only if outliers exist (they atomically accumulate into it).
// ---------------------------------------------------------------------------
__global__ __launch_bounds__(TPB) void cond_zero_kernel(
    float4* __restrict__ out4, const unsigned* __restrict__ flag)
{
    if (*flag == 0u) return;
    const int n4 = BB * CHW / 4;
    for (int i = blockIdx.x * TPB + threadIdx.x; i < n4; i += gridDim.x * TPB)
        out4[i] = float4{0.f, 0.f, 0.f, 0.f};
}

// ---------------------------------------------------------------------------
// K3: rare-path scatter for outlier sources (global atomics, ~0 pixels usually).
// ---------------------------------------------------------------------------
__global__ __launch_bounds__(TPB) void outlier_kernel(
    const float* __restrict__ inp, const float* __restrict__ flow,
    const float* __restrict__ mask, float* __restrict__ acc,
    float* __restrict__ wacc, const unsigned* __restrict__ flag)
{
    if (*flag == 0u) return;
    int p = blockIdx.x * TPB + threadIdx.x;
    if (p >= BB * HW) return;
    int b = p / HW, rem = p - b * HW;
    int y = rem / WW, x = rem - y * WW;

    float dx = flow[(b * 2 + 0) * HW + rem];
    float dy = flow[(b * 2 + 1) * HW + rem];
    if ((fabsf(dx) <= LOCAL_MAX) && (fabsf(dy) <= LOCAL_MAX)) return; // local: gather handles

    float tx = (float)x + dx, ty = (float)y + dy;
    float x0f = floorf(tx), y0f = floorf(ty);
    int   x0 = (int)x0f, y0 = (int)y0f;
    float fx = tx - x0f, fy = ty - y0f;
    float wx[2] = {1.0f - fx, fx};
    float wy[2] = {1.0f - fy, fy};
    float m = expf(mask[b * HW + rem]);

    int   cidx[4];
    float cw[4];
    bool  cv[4];
#pragma unroll
    for (int j = 0; j < 4; ++j) {
        int xi = x0 + (j & 1), yi = y0 + (j >> 1);
        cv[j]   = (xi >= 0) & (xi < WW) & (yi >= 0) & (yi < HH);
        cidx[j] = yi * WW + xi;
        cw[j]   = wx[j & 1] * wy[j >> 1] * m;
    }
    float* wbase = wacc + b * HW;
#pragma unroll
    for (int j = 0; j < 4; ++j)
        if (cv[j]) unsafeAtomicAdd(wbase + cidx[j], cw[j]);
    const float* ibase = inp + b * CHW + rem;
    float*       obase = acc + b * CHW;
    for (int c = 0; c < CC; ++c) {
        float v = ibase[c * HW];
#pragma unroll
        for (int j = 0; j < 4; ++j)
            if (cv[j]) unsafeAtomicAdd(obase + c * HW + cidx[j], cw[j] * v);
    }
}

// ---------------------------------------------------------------------------
// K4: gather-splat with wave-level stream compaction.
// Phase A: scan window slots, ballot-compact passing sources into an LDS
//          list {packed(sp,lx,ly), w4}.
// Phase B: dense waves drain the list: 8 value loads + 36 ds_add each.
// Then fused normalize + coalesced stores.
// ---------------------------------------------------------------------------
__global__ __launch_bounds__(TPB, 4) void gather_kernel(
    const float* __restrict__ inp, const float* __restrict__ flow,
    const float* __restrict__ mask, float* __restrict__ out,
    const float* __restrict__ wacc, const unsigned* __restrict__ flag)
{
    __shared__ float  lds[(1 + NCH) * TXTY];  // [0,TXTY) weights, then NCH planes
    __shared__ int    s_meta[CAP];            // sp | (lx+1)<<17 | (ly+1)<<23
    __shared__ float4 s_w4[CAP];
    __shared__ int    s_n;
    float* wlds = lds;

    const int b    = blockIdx.z >> 3;
    const int grp  = blockIdx.z & 7;
    const int bx0  = blockIdx.x * TX;
    const int by0  = blockIdx.y * TY;
    const int tid  = threadIdx.x;
    const int lane = tid & 63;

    // zero accumulation planes
    {
        float4* z = (float4*)lds;
        constexpr int n4 = (1 + NCH) * TXTY / 4;   // 1152
#pragma unroll
        for (int i = 0; i < (n4 + TPB - 1) / TPB; ++i) {
            int idx = tid + i * TPB;
            if (idx < n4) z[idx] = float4{0.f, 0.f, 0.f, 0.f};
        }
    }

    const float* __restrict__ fxp = flow + (b * 2 + 0) * HW;
    const float* __restrict__ fyp = flow + (b * 2 + 1) * HW;
    const float* __restrict__ mp  = mask + b * HW;
    const float* __restrict__ ib  = inp + (b * CC + grp * NCH) * HW;

    for (int r = 0; r < NROUND; ++r) {
        if (tid == 0) s_n = 0;
        __syncthreads();   // covers plane zeroing (r==0) and s_n reset

        // ---- Phase A: scan + compact -------------------------------------
#pragma unroll
        for (int k = 0; k < KCH; ++k) {
            const int s  = (r * KCH + k) * TPB + tid;
            const int sy = s / WINX;
            const int sx = s - sy * WINX;
            const int gx = bx0 - TH + sx;
            const int gy = by0 - TH + sy;
            bool pass = (s < NSRC) & (gx >= 0) & (gx < WW) & (gy >= 0) & (gy < HH);
            const int sp = gy * WW + gx;
            float dx = 0.f, dy = 0.f;
            if (pass) {
                dx = fxp[sp];
                dy = fyp[sp];
                pass = (fabsf(dx) <= LOCAL_MAX) && (fabsf(dy) <= LOCAL_MAX);
            }
            const float tx  = (float)gx + dx;
            const float ty  = (float)gy + dy;
            const float x0f = floorf(tx), y0f = floorf(ty);
            const int   lx  = (int)x0f - bx0;
            const int   ly  = (int)y0f - by0;
            pass = pass && (lx >= -1) && (lx < TX) && (ly >= -1) && (ly < TY);

            float m = 0.f;
            if (pass) m = expf(mp[sp]);
            const float fx = tx - x0f, fy = ty - y0f;
            const float ox = 1.0f - fx, oy = 1.0f - fy;

            const unsigned long long ball = __ballot(pass);
            int base = 0;
            if (lane == 0) base = atomicAdd(&s_n, (int)__popcll(ball));
            base = __shfl(base, 0);
            if (pass) {
                const int pos = base + (int)__popcll(ball & ((1ull << lane) - 1ull));
                s_meta[pos] = sp | ((lx + 1) << 17) | ((ly + 1) << 23);
                s_w4[pos]   = float4{ox * oy * m, fx * oy * m, ox * fy * m, fx * fy * m};
            }
        }
        __syncthreads();

        // ---- Phase B: dense drain ----------------------------------------
        const int n = s_n;
        for (int i = tid; i < n; i += TPB) {
            const int   meta = s_meta[i];
            const int   sp   = meta & 0x1ffff;
            const int   lx   = ((meta >> 17) & 0x3f) - 1;
            const int   ly   = ((meta >> 23) & 0x1f) - 1;
            const float4 w4  = s_w4[i];
            float vv[NCH];
#pragma unroll
            for (int c = 0; c < NCH; ++c) vv[c] = ib[c * HW + sp];
            const float w[4] = {w4.x, w4.y, w4.z, w4.w};
#pragma unroll
            for (int j = 0; j < 4; ++j) {
                const int cx = lx + (j & 1), cy = ly + (j >> 1);
                if (cx >= 0 && cx < TX && cy >= 0 && cy < TY) {
                    const int li = cy * TX + cx;
                    atomicAdd(&wlds[li], w[j]);
                    float* vp = &lds[TXTY + li];
#pragma unroll
                    for (int c = 0; c < NCH; ++c)
                        atomicAdd(vp + c * TXTY, w[j] * vv[c]);
                }
            }
        }
        __syncthreads();
    }

    // ---- normalize + store (2 pixels per thread x 8 channels) ------------
    const bool has_out = (*flag != 0u);
    const int  obase   = (b * CC + grp * NCH) * HW;
#pragma unroll
    for (int t = 0; t < 2; ++t) {
        const int p  = tid + t * TPB;
        const int py = p >> 5, px = p & 31;           // TX = 32
        const int gpix = (by0 + py) * WW + (bx0 + px);
        const float rden = 1.0f / (wlds[p] + wacc[b * HW + gpix] + 1e-7f);
#pragma unroll
        for (int c = 0; c < NCH; ++c) {
            float a = lds[TXTY + c * TXTY + p];
            const int gi = obase + c * HW + gpix;
            if (has_out) a += out[gi];                 // rare outlier contributions
            out[gi] = a * rden;
        }
    }
}

extern "C" void kernel_launch(void* const* d_in, const int* in_sizes, int n_in,
                              void* d_out, int out_size, void* d_ws, size_t ws_size,
                              hipStream_t stream) {
    const float* inp  = (const float*)d_in[0];  // [4,64,256,448]
    const float* flow = (const float*)d_in[1];  // [4,2,256,448]
    const float* mask = (const float*)d_in[2];  // [4,1,256,448]
    float*    out  = (float*)d_out;
    float*    wacc = (float*)d_ws;                          // [B,HW] outlier weights
    unsigned* flag = (unsigned*)((float*)d_ws + BB * HW);   // outlier flag

    // zero wacc + flag every call (deterministic under graph replay)
    hipMemsetAsync(d_ws, 0, (size_t)(BB * HW + 4) * sizeof(float), stream);

    const int npix = BB * HW;
    flag_kernel<<<(npix + TPB - 1) / TPB, TPB, 0, stream>>>(flow, flag);
    cond_zero_kernel<<<2048, TPB, 0, stream>>>((float4*)out, flag);
    outlier_kernel<<<(npix + TPB - 1) / TPB, TPB, 0, stream>>>(inp, flow, mask, out, wacc, flag);
    gather_kernel<<<dim3(WW / TX, HH / TY, BB * NGRP), TPB, 0, stream>>>(inp, flow, mask, out, wacc, flag);
}